// Round 3
// baseline (71.521 us; speedup 1.0000x reference)
//
#include <hip/hip_runtime.h>

// CrossAttentionBlock, collapsed form:
//   softmax over a single KV token == 1.0  =>  attn output per (b,s) = v[b] (C-vector)
//   a[b] = (text_emb[b] @ Wv.T) @ Wo.T + bo          (per-batch, s-independent)
//   y[b,c,s] = LN_c(x[b,c,s] + a[b,c]) * gamma[c] + beta[c]   (LN over C per (b,s))
// Wq, Wk are dead.

constexpr int B = 16, C = 512, T = 768, S = 4096;
constexpr float LN_EPS = 1e-5f;

// ---------------- wave-per-output GEMV: out[b][c] = row_b(in) . row_c(Wt) + bias[c] ----
template <int K, bool HAS_BIAS>
__global__ __launch_bounds__(256) void gemv_wave(const float* __restrict__ in,
                                                 const float* __restrict__ Wt,
                                                 const float* __restrict__ bias,
                                                 float* __restrict__ out) {
    const int w    = blockIdx.x * 4 + (threadIdx.x >> 6);
    const int lane = threadIdx.x & 63;
    const int b    = w >> 9;          // / C
    const int c    = w & (C - 1);
    const float4* wr = reinterpret_cast<const float4*>(Wt + (size_t)c * K);
    const float4* xr = reinterpret_cast<const float4*>(in + (size_t)b * K);
    float acc = 0.f;
#pragma unroll
    for (int i = lane; i < K / 4; i += 64) {
        float4 a = wr[i], t = xr[i];
        acc += a.x * t.x + a.y * t.y + a.z * t.z + a.w * t.w;
    }
#pragma unroll
    for (int off = 32; off > 0; off >>= 1) acc += __shfl_down(acc, off);
    if (lane == 0) out[b * C + c] = HAS_BIAS ? acc + bias[c] : acc;
}

// ---------------- fused broadcast-add + LayerNorm over C, register-resident ----------
// Block: 512 threads; tile = (b, s0..s0+15), all 512 channels.
// Thread t: s4 = t&3 (one float4 of s), m = t>>2; owns rows c = m + 128*i, i<4.
// x kept in 4 float4 registers; per-s stats via shfl_xor over the 16 lanes sharing s4.
__global__ __launch_bounds__(512) void fused_ln(const float* __restrict__ x,
                                                const float* __restrict__ a,
                                                const float* __restrict__ gamma,
                                                const float* __restrict__ beta,
                                                float* __restrict__ out) {
    __shared__ float a_s[C], g_s[C], be_s[C];   // 6 KB
    __shared__ float4 ps[32], pq[32];           // 8 waves x 4 s4, 1 KB

    const int bid = blockIdx.x;
    const int b   = bid >> 8;            // 256 tiles per batch
    const int s0  = (bid & 255) << 4;    // * 16
    const int t   = threadIdx.x;
    const int s4  = t & 3;
    const int m   = t >> 2;              // 0..127

    const float4* xb4 = reinterpret_cast<const float4*>(x + (size_t)b * C * S + s0);
    float4 xv[4];
#pragma unroll
    for (int i = 0; i < 4; ++i)
        xv[i] = xb4[(size_t)(m + 128 * i) * (S / 4) + s4];

    // stage per-channel params, coalesced (t covers 0..511 == C)
    a_s[t]  = a[b * C + t];
    g_s[t]  = gamma[t];
    be_s[t] = beta[t];
    __syncthreads();

    float4 sum4 = {0.f, 0.f, 0.f, 0.f}, sq4 = {0.f, 0.f, 0.f, 0.f};
#pragma unroll
    for (int i = 0; i < 4; ++i) {
        const float ac = a_s[m + 128 * i];
        xv[i].x += ac; xv[i].y += ac; xv[i].z += ac; xv[i].w += ac;
        sum4.x += xv[i].x; sum4.y += xv[i].y; sum4.z += xv[i].z; sum4.w += xv[i].w;
        sq4.x  += xv[i].x * xv[i].x; sq4.y += xv[i].y * xv[i].y;
        sq4.z  += xv[i].z * xv[i].z; sq4.w += xv[i].w * xv[i].w;
    }

    // reduce across the 16 lanes of this wave that share s4 (lane bits 2..5)
#pragma unroll
    for (int mask = 4; mask <= 32; mask <<= 1) {
        sum4.x += __shfl_xor(sum4.x, mask); sum4.y += __shfl_xor(sum4.y, mask);
        sum4.z += __shfl_xor(sum4.z, mask); sum4.w += __shfl_xor(sum4.w, mask);
        sq4.x  += __shfl_xor(sq4.x,  mask); sq4.y  += __shfl_xor(sq4.y,  mask);
        sq4.z  += __shfl_xor(sq4.z,  mask); sq4.w  += __shfl_xor(sq4.w,  mask);
    }
    const int w = t >> 6, l = t & 63;
    if (l < 4) { ps[w * 4 + l] = sum4; pq[w * 4 + l] = sq4; }
    __syncthreads();

    // every thread combines the 8 wave-partials for its s4 (broadcast LDS reads)
    float4 tot = {0.f, 0.f, 0.f, 0.f}, tq = {0.f, 0.f, 0.f, 0.f};
#pragma unroll
    for (int wv = 0; wv < 8; ++wv) {
        float4 p = ps[wv * 4 + s4];
        float4 q = pq[wv * 4 + s4];
        tot.x += p.x; tot.y += p.y; tot.z += p.z; tot.w += p.w;
        tq.x  += q.x; tq.y  += q.y; tq.z  += q.z; tq.w  += q.w;
    }
    constexpr float inv = 1.f / C;
    float4 mu, rs;
    mu.x = tot.x * inv; mu.y = tot.y * inv; mu.z = tot.z * inv; mu.w = tot.w * inv;
    rs.x = rsqrtf(tq.x * inv - mu.x * mu.x + LN_EPS);
    rs.y = rsqrtf(tq.y * inv - mu.y * mu.y + LN_EPS);
    rs.z = rsqrtf(tq.z * inv - mu.z * mu.z + LN_EPS);
    rs.w = rsqrtf(tq.w * inv - mu.w * mu.w + LN_EPS);

    float4* ob4 = reinterpret_cast<float4*>(out + (size_t)b * C * S + s0);
#pragma unroll
    for (int i = 0; i < 4; ++i) {
        const int c = m + 128 * i;
        const float g = g_s[c], be = be_s[c];
        float4 v = xv[i], o;
        o.x = (v.x - mu.x) * rs.x * g + be;
        o.y = (v.y - mu.y) * rs.y * g + be;
        o.z = (v.z - mu.z) * rs.z * g + be;
        o.w = (v.w - mu.w) * rs.w * g + be;
        ob4[(size_t)c * (S / 4) + s4] = o;
    }
}

extern "C" void kernel_launch(void* const* d_in, const int* in_sizes, int n_in,
                              void* d_out, int out_size, void* d_ws, size_t ws_size,
                              hipStream_t stream) {
    const float* x     = (const float*)d_in[0];
    const float* te    = (const float*)d_in[1];
    // d_in[2] = Wq, d_in[3] = Wk: dead (softmax over single KV token == 1)
    const float* Wv    = (const float*)d_in[4];
    const float* Wo    = (const float*)d_in[5];
    const float* bo    = (const float*)d_in[6];
    const float* gamma = (const float*)d_in[7];
    const float* beta  = (const float*)d_in[8];
    float* out = (float*)d_out;
    float* v   = (float*)d_ws;              // 16*512 floats
    float* a   = (float*)d_ws + B * C;      // 16*512 floats

    gemv_wave<T, false><<<B * C / 4, 256, 0, stream>>>(te, Wv, nullptr, v);
    gemv_wave<C, true ><<<B * C / 4, 256, 0, stream>>>(v,  Wo, bo,      a);
    fused_ln<<<B * (S / 16), 512, 0, stream>>>(x, a, gamma, beta, out);
}

// Round 4
// 52.301 us; speedup vs baseline: 1.3675x; 1.3675x over previous
//
#include <hip/hip_runtime.h>

// CrossAttentionBlock, collapsed form:
//   softmax over a single KV token == 1.0  =>  attn output per (b,s) = v[b] (C-vector)
//   a[b] = (text_emb[b] @ Wv.T) @ Wo.T + bo          (per-batch, s-independent)
//   y[b,c,s] = LN_c(x[b,c,s] + a[b,c]) * gamma[c] + beta[c]   (LN over C per (b,s))
// Wq, Wk are dead.

constexpr int B = 16, C = 512, T = 768, S = 4096;
constexpr float LN_EPS = 1e-5f;

typedef float v4f __attribute__((ext_vector_type(4)));

// ---------------- wave-per-output GEMV: out[b][c] = row_b(in) . row_c(Wt) + bias[c] ----
template <int K, bool HAS_BIAS>
__global__ __launch_bounds__(256) void gemv_wave(const float* __restrict__ in,
                                                 const float* __restrict__ Wt,
                                                 const float* __restrict__ bias,
                                                 float* __restrict__ out) {
    const int w    = blockIdx.x * 4 + (threadIdx.x >> 6);
    const int lane = threadIdx.x & 63;
    const int b    = w >> 9;          // / C
    const int c    = w & (C - 1);
    const float4* wr = reinterpret_cast<const float4*>(Wt + (size_t)c * K);
    const float4* xr = reinterpret_cast<const float4*>(in + (size_t)b * K);
    float acc = 0.f;
#pragma unroll
    for (int i = lane; i < K / 4; i += 64) {
        float4 a = wr[i], t = xr[i];
        acc += a.x * t.x + a.y * t.y + a.z * t.z + a.w * t.w;
    }
#pragma unroll
    for (int off = 32; off > 0; off >>= 1) acc += __shfl_down(acc, off);
    if (lane == 0) out[b * C + c] = HAS_BIAS ? acc + bias[c] : acc;
}

// ---------------- fused broadcast-add + LayerNorm over C, register-resident ----------
// Block: 1024 threads (16 waves); tile = (b, s0..s0+63, all 512 channels).
// Thread t: q = t&15 (one float4 of s), m = t>>4 (0..63); owns rows c = m + 64*i, i<8.
// Wave load granularity: 4 rows x 256 B contiguous. x held in 8 float4 registers.
// out written with non-temporal stores (evict-first) so the 128 MiB write stream
// does not evict x from the 256 MiB Infinity Cache between graph replays.
__global__ __launch_bounds__(1024) void fused_ln(const float* __restrict__ x,
                                                 const float* __restrict__ a,
                                                 const float* __restrict__ gamma,
                                                 const float* __restrict__ beta,
                                                 float* __restrict__ out) {
    __shared__ float a_s[C], g_s[C], be_s[C];     // 6 KB
    __shared__ float4 ps[16 * 16], pq[16 * 16];   // 16 waves x 16 q, 8 KB

    const int bid = blockIdx.x;
    const int b   = bid >> 6;            // 64 tiles per batch
    const int s0  = (bid & 63) << 6;     // * 64
    const int t   = threadIdx.x;
    const int q   = t & 15;
    const int m   = t >> 4;              // 0..63

    const float4* xb4 = reinterpret_cast<const float4*>(x + (size_t)b * C * S + s0);
    float4 xv[8];
#pragma unroll
    for (int i = 0; i < 8; ++i)
        xv[i] = xb4[(size_t)(m + 64 * i) * (S / 4) + q];

    if (t < C) {
        a_s[t]  = a[b * C + t];
        g_s[t]  = gamma[t];
        be_s[t] = beta[t];
    }
    __syncthreads();

    float4 sum4 = {0.f, 0.f, 0.f, 0.f}, sq4 = {0.f, 0.f, 0.f, 0.f};
#pragma unroll
    for (int i = 0; i < 8; ++i) {
        const float ac = a_s[m + 64 * i];
        xv[i].x += ac; xv[i].y += ac; xv[i].z += ac; xv[i].w += ac;
        sum4.x += xv[i].x; sum4.y += xv[i].y; sum4.z += xv[i].z; sum4.w += xv[i].w;
        sq4.x  += xv[i].x * xv[i].x; sq4.y += xv[i].y * xv[i].y;
        sq4.z  += xv[i].z * xv[i].z; sq4.w  += xv[i].w * xv[i].w;
    }

    // combine the 4 lanes of this wave that share q (lane bits 4,5)
#pragma unroll
    for (int mask = 16; mask <= 32; mask <<= 1) {
        sum4.x += __shfl_xor(sum4.x, mask); sum4.y += __shfl_xor(sum4.y, mask);
        sum4.z += __shfl_xor(sum4.z, mask); sum4.w += __shfl_xor(sum4.w, mask);
        sq4.x  += __shfl_xor(sq4.x,  mask); sq4.y  += __shfl_xor(sq4.y,  mask);
        sq4.z  += __shfl_xor(sq4.z,  mask); sq4.w  += __shfl_xor(sq4.w,  mask);
    }
    const int w = t >> 6, l = t & 63;
    if (l < 16) { ps[w * 16 + l] = sum4; pq[w * 16 + l] = sq4; }
    __syncthreads();

    // every thread combines the 16 wave-partials for its q (broadcast LDS reads)
    float4 tot = {0.f, 0.f, 0.f, 0.f}, tq = {0.f, 0.f, 0.f, 0.f};
#pragma unroll
    for (int wv = 0; wv < 16; ++wv) {
        float4 p = ps[wv * 16 + q];
        float4 s = pq[wv * 16 + q];
        tot.x += p.x; tot.y += p.y; tot.z += p.z; tot.w += p.w;
        tq.x  += s.x; tq.y  += s.y; tq.z  += s.z; tq.w  += s.w;
    }
    constexpr float inv = 1.f / C;
    float4 mu, rs;
    mu.x = tot.x * inv; mu.y = tot.y * inv; mu.z = tot.z * inv; mu.w = tot.w * inv;
    rs.x = rsqrtf(tq.x * inv - mu.x * mu.x + LN_EPS);
    rs.y = rsqrtf(tq.y * inv - mu.y * mu.y + LN_EPS);
    rs.z = rsqrtf(tq.z * inv - mu.z * mu.z + LN_EPS);
    rs.w = rsqrtf(tq.w * inv - mu.w * mu.w + LN_EPS);

    float4* ob4 = reinterpret_cast<float4*>(out + (size_t)b * C * S + s0);
#pragma unroll
    for (int i = 0; i < 8; ++i) {
        const int c = m + 64 * i;
        const float g = g_s[c], be = be_s[c];
        float4 v = xv[i], o;
        o.x = (v.x - mu.x) * rs.x * g + be;
        o.y = (v.y - mu.y) * rs.y * g + be;
        o.z = (v.z - mu.z) * rs.z * g + be;
        o.w = (v.w - mu.w) * rs.w * g + be;
        __builtin_nontemporal_store(*reinterpret_cast<const v4f*>(&o),
            reinterpret_cast<v4f*>(&ob4[(size_t)c * (S / 4) + q]));
    }
}

extern "C" void kernel_launch(void* const* d_in, const int* in_sizes, int n_in,
                              void* d_out, int out_size, void* d_ws, size_t ws_size,
                              hipStream_t stream) {
    const float* x     = (const float*)d_in[0];
    const float* te    = (const float*)d_in[1];
    // d_in[2] = Wq, d_in[3] = Wk: dead (softmax over single KV token == 1)
    const float* Wv    = (const float*)d_in[4];
    const float* Wo    = (const float*)d_in[5];
    const float* bo    = (const float*)d_in[6];
    const float* gamma = (const float*)d_in[7];
    const float* beta  = (const float*)d_in[8];
    float* out = (float*)d_out;
    float* v   = (float*)d_ws;              // 16*512 floats
    float* a   = (float*)d_ws + B * C;      // 16*512 floats

    gemv_wave<T, false><<<B * C / 4, 256, 0, stream>>>(te, Wv, nullptr, v);
    gemv_wave<C, true ><<<B * C / 4, 256, 0, stream>>>(v,  Wo, bo,      a);
    fused_ln<<<B * (S / 64), 1024, 0, stream>>>(x, a, gamma, beta, out);
}